// Round 8
// baseline (464.625 us; speedup 1.0000x reference)
//
#include <hip/hip_runtime.h>
#include <hip/hip_bf16.h>

#define LRALPHA 0.2f
#define L2E 1.4426950408889634f
#define NN 8192
#define FIN 128
#define FOUT 64
#define TI 16
#define TJ 256
#define NTL (NN / TJ)       // 32 tiles of 256 cols
#define TPB 16              // tiles per block (j-range split in half)
#define DIAG_REPS 4         // DIAGNOSTIC: repeat compress & gat_main 4x so
                            // their dispatches exceed the ~155us fill-kernel
                            // floor and show up in rocprof top-5 w/ counters

typedef __attribute__((ext_vector_type(4))) float f32x4;
typedef __attribute__((ext_vector_type(8))) short bf16x8;
typedef __attribute__((ext_vector_type(4))) int int4v;

__device__ __forceinline__ void barrier_lgkm() {
  asm volatile("s_waitcnt lgkmcnt(0)\n\ts_barrier" ::: "memory");
}

// ---------------------------------------------------------------------------
// kernel 0: adj (268 MB int32) -> 1-bit mask (8 MB), m13-copy shape.
// DIAG: x4 internal reps (idempotent).
// ---------------------------------------------------------------------------
__global__ __launch_bounds__(256) void compress_kernel(
    const int* __restrict__ adj, unsigned char* __restrict__ maskb)
{
  const int nthr = gridDim.x * 256;
  const int total = NN * (NN / 8);              // 8,388,608 byte-slots
  for (int rep = 0; rep < DIAG_REPS; ++rep) {
    asm volatile("" ::: "memory");              // no hoisting across reps
#pragma unroll 2
    for (int idx = blockIdx.x * 256 + threadIdx.x; idx < total; idx += nthr) {
      int4v v0 = *(const int4v*)(adj + (size_t)idx * 8);
      int4v v1 = *(const int4v*)(adj + (size_t)idx * 8 + 4);
      unsigned b =
          (v0[0] > 0 ? 1u : 0u)  | (v0[1] > 0 ? 2u : 0u) |
          (v0[2] > 0 ? 4u : 0u)  | (v0[3] > 0 ? 8u : 0u) |
          (v1[0] > 0 ? 16u : 0u) | (v1[1] > 0 ? 32u : 0u) |
          (v1[2] > 0 ? 64u : 0u) | (v1[3] > 0 ? 128u : 0u);
      maskb[idx] = (unsigned char)b;
    }
  }
}

// ---------------------------------------------------------------------------
// kernel 1: h = inp @ W (fp32), f1/f2 (prescaled by log2(e)), hT bf16
// ---------------------------------------------------------------------------
__global__ __launch_bounds__(256) void prep_kernel(
    const float* __restrict__ inp, const float* __restrict__ Wg,
    const float* __restrict__ ag, float* __restrict__ f1,
    float* __restrict__ f2, unsigned short* __restrict__ hT)
{
  __shared__ alignas(16) float WlT[FOUT][FIN + 4];
  const int t = threadIdx.x;
  for (int i = t; i < FIN * FOUT; i += 256)
    WlT[i & 63][i >> 6] = Wg[i];
  __syncthreads();

  const int lane = t & 63;
  const int row0 = blockIdx.x * 16 + (t >> 6) * 4;

  float h0 = 0.f, h1 = 0.f, h2 = 0.f, h3 = 0.f;
  for (int kk = 0; kk < FIN; kk += 4) {
    f32x4 wv = *(const f32x4*)&WlT[lane][kk];
    f32x4 r0 = *(const f32x4*)&inp[(row0 + 0) * FIN + kk];
    f32x4 r1 = *(const f32x4*)&inp[(row0 + 1) * FIN + kk];
    f32x4 r2 = *(const f32x4*)&inp[(row0 + 2) * FIN + kk];
    f32x4 r3 = *(const f32x4*)&inp[(row0 + 3) * FIN + kk];
    h0 += r0[0]*wv[0] + r0[1]*wv[1] + r0[2]*wv[2] + r0[3]*wv[3];
    h1 += r1[0]*wv[0] + r1[1]*wv[1] + r1[2]*wv[2] + r1[3]*wv[3];
    h2 += r2[0]*wv[0] + r2[1]*wv[1] + r2[2]*wv[2] + r2[3]*wv[3];
    h3 += r3[0]*wv[0] + r3[1]*wv[1] + r3[2]*wv[2] + r3[3]*wv[3];
  }

  const float a1v = ag[lane], a2v = ag[64 + lane];
  float hv[4] = {h0, h1, h2, h3};
#pragma unroll
  for (int rr = 0; rr < 4; ++rr) {
    float c1 = hv[rr] * a1v;
    float c2 = hv[rr] * a2v;
#pragma unroll
    for (int off = 32; off > 0; off >>= 1) {
      c1 += __shfl_xor(c1, off);
      c2 += __shfl_xor(c2, off);
    }
    if (lane == 0) { f1[row0 + rr] = c1 * L2E; f2[row0 + rr] = c2 * L2E; }
    __hip_bfloat16 hb = __float2bfloat16(hv[rr]);
    hT[lane * NN + row0 + rr] = __builtin_bit_cast(unsigned short, hb);
  }
}

// ---------------------------------------------------------------------------
// kernel 2: global max of (scaled) f2
// ---------------------------------------------------------------------------
__global__ __launch_bounds__(256) void f2max_kernel(
    const float* __restrict__ f2, float* __restrict__ f2m)
{
  const int t = threadIdx.x;
  float m = -1e30f;
  for (int i = t; i < NN / 4; i += 256) {
    f32x4 v = ((const f32x4*)f2)[i];
    m = fmaxf(fmaxf(m, fmaxf(v[0], v[1])), fmaxf(v[2], v[3]));
  }
#pragma unroll
  for (int off = 32; off > 0; off >>= 1)
    m = fmaxf(m, __shfl_xor(m, off));
  __shared__ float ms[4];
  if ((t & 63) == 0) ms[t >> 6] = m;
  __syncthreads();
  if (t == 0)
    f2m[0] = fmaxf(fmaxf(ms[0], ms[1]), fmaxf(ms[2], ms[3]));
}

// ---------------------------------------------------------------------------
// kernel 3: masked-softmax attention PV (R7 math, bit-identical per rep).
// DIAG: x4 internal reps, acc/rs reset per rep, stores inside rep loop so
// nothing is dead-code-eliminated.
// ---------------------------------------------------------------------------
__global__ __launch_bounds__(256, 4) void gat_main(
    const unsigned long long* __restrict__ mask,
    const float* __restrict__ f1g, const float* __restrict__ f2g,
    const float* __restrict__ f2m, const unsigned short* __restrict__ hTg,
    float* __restrict__ pacc, float* __restrict__ prs)
{
  __shared__ alignas(16) unsigned short Pl[4][TI][TJ + 8];

  const int t = threadIdx.x;
  const int l = t & 63;
  const int w = t >> 6;
  const int rb = blockIdx.x >> 1;
  const int h  = blockIdx.x & 1;
  const int i0 = rb * TI;
  const int g  = l >> 4;
  const int p0t = h * TPB;

  const float fmv = f2m[0];
  float c1q[4], c2q[4];
#pragma unroll
  for (int q = 0; q < 4; ++q) {
    float f1s = f1g[i0 + 4 * w + q];
    float M = f1s + fmv;
    float mr = fmaxf(M, LRALPHA * M);
    c1q[q] = f1s - mr;
    c2q[q] = LRALPHA * f1s - mr;
  }

  const unsigned long long* mr0 = mask + ((size_t)(i0 + 4*w + 0) * NTL) * 4 + g;
  const unsigned long long* mr1 = mask + ((size_t)(i0 + 4*w + 1) * NTL) * 4 + g;
  const unsigned long long* mr2 = mask + ((size_t)(i0 + 4*w + 2) * NTL) * 4 + g;
  const unsigned long long* mr3 = mask + ((size_t)(i0 + 4*w + 3) * NTL) * 4 + g;
  const int mshift = (l & 15) * 4;

  const float* f2p = f2g + 4 * l;
  const unsigned short* hp = hTg + (size_t)(w * 16 + (l & 15)) * NN + g * 8;

#define PRODUCE(K, MM0, MM1, MM2, MM3, FF)                                     \
  {                                                                            \
    float F5x = LRALPHA * FF[0], F5y = LRALPHA * FF[1],                        \
          F5z = LRALPHA * FF[2], F5w = LRALPHA * FF[3];                        \
    _Pragma("unroll")                                                          \
    for (int q = 0; q < 4; ++q) {                                              \
      unsigned long long mm = q == 0 ? MM0 : q == 1 ? MM1 : q == 2 ? MM2 : MM3;\
      unsigned nib = (unsigned)(mm >> mshift) & 0xFu;                          \
      float z0 = fmaxf(c1q[q] + FF[0], c2q[q] + F5x);                          \
      float z1 = fmaxf(c1q[q] + FF[1], c2q[q] + F5y);                          \
      float z2 = fmaxf(c1q[q] + FF[2], c2q[q] + F5z);                          \
      float z3 = fmaxf(c1q[q] + FF[3], c2q[q] + F5w);                          \
      z0 = (nib & 1u) ? z0 : -1000.f;                                          \
      z1 = (nib & 2u) ? z1 : -1000.f;                                          \
      z2 = (nib & 4u) ? z2 : -1000.f;                                          \
      z3 = (nib & 8u) ? z3 : -1000.f;                                          \
      float p0 = __builtin_amdgcn_exp2f(z0);                                   \
      float p1 = __builtin_amdgcn_exp2f(z1);                                   \
      float p2 = __builtin_amdgcn_exp2f(z2);                                   \
      float p3 = __builtin_amdgcn_exp2f(z3);                                   \
      float pS = (p0 + p1) + (p2 + p3);                                        \
      if (q == 0) rs0 += pS;                                                   \
      else if (q == 1) rs1 += pS;                                              \
      else if (q == 2) rs2 += pS;                                              \
      else rs3 += pS;                                                          \
      unsigned r0 = __builtin_bit_cast(unsigned, p0) + 0x8000u;                \
      unsigned r1 = __builtin_bit_cast(unsigned, p1) + 0x8000u;                \
      unsigned r2 = __builtin_bit_cast(unsigned, p2) + 0x8000u;                \
      unsigned r3 = __builtin_bit_cast(unsigned, p3) + 0x8000u;                \
      unsigned pk01 = __builtin_amdgcn_perm(r1, r0, 0x07060302u);              \
      unsigned pk23 = __builtin_amdgcn_perm(r3, r2, 0x07060302u);              \
      unsigned long long pk = (unsigned long long)pk01 |                       \
                              ((unsigned long long)pk23 << 32);                \
      *(unsigned long long*)&Pl[(K) & 3][4 * w + q][4 * l] = pk;               \
    }                                                                          \
  }

#define LOADR(MM0, MM1, MM2, MM3, FF, K)                                       \
  { int _k = (K) < TPB ? (K) : (TPB - 1);                                      \
    int _p = p0t + _k;                                                         \
    MM0 = mr0[_p * 4]; MM1 = mr1[_p * 4];                                      \
    MM2 = mr2[_p * 4]; MM3 = mr3[_p * 4];                                      \
    FF = *(const f32x4*)(f2p + _p * TJ); }

  for (int rep = 0; rep < DIAG_REPS; ++rep) {
    asm volatile("" ::: "memory");
    __syncthreads();

    f32x4 acc = {0.f, 0.f, 0.f, 0.f};
    float rs0 = 0.f, rs1 = 0.f, rs2 = 0.f, rs3 = 0.f;
    unsigned long long m0, m1, m2, m3;
    f32x4 ff;

    LOADR(m0, m1, m2, m3, ff, 0);
    PRODUCE(0, m0, m1, m2, m3, ff);
    LOADR(m0, m1, m2, m3, ff, 1);
    PRODUCE(1, m0, m1, m2, m3, ff);
    LOADR(m0, m1, m2, m3, ff, 2);

    for (int k = 0; k < TPB; ++k) {
      if (k < TPB - 2) {
        PRODUCE(k + 2, m0, m1, m2, m3, ff);
        LOADR(m0, m1, m2, m3, ff, k + 3);
      }
      barrier_lgkm();
      const unsigned short* pa = &Pl[k & 3][0][0] + (l & 15) * (TJ + 8) + g * 8;
      const unsigned short* pb = hp + (size_t)(p0t + k) * TJ;
#pragma unroll
      for (int kw = 0; kw < 8; ++kw) {
        bf16x8 av = *(const bf16x8*)(pa + kw * 32);
        bf16x8 bv = *(const bf16x8*)(pb + kw * 32);
        acc = __builtin_amdgcn_mfma_f32_16x16x32_bf16(av, bv, acc, 0, 0, 0);
      }
    }

    // wave-level row sums -> partial rs (stores inside rep: no DCE)
    float rsq[4] = {rs0, rs1, rs2, rs3};
#pragma unroll
    for (int q = 0; q < 4; ++q) {
      float r = rsq[q];
#pragma unroll
      for (int off = 32; off > 0; off >>= 1)
        r += __shfl_xor(r, off);
      if (l == 0) prs[(size_t)h * NN + i0 + 4 * w + q] = r;
    }

    float* po = pacc + (size_t)h * NN * FOUT
              + (size_t)(i0 + g * 4) * FOUT + (w * 16 + (l & 15));
#pragma unroll
    for (int q = 0; q < 4; ++q)
      po[(size_t)q * FOUT] = acc[q];
  }
#undef PRODUCE
#undef LOADR
}

// ---------------------------------------------------------------------------
// kernel 4: combine halves, BN, ELU
// ---------------------------------------------------------------------------
__global__ __launch_bounds__(256) void epilogue_kernel(
    const float* __restrict__ pacc, const float* __restrict__ prs,
    const float* __restrict__ bng, const float* __restrict__ bnb,
    const float* __restrict__ bnm, const float* __restrict__ bnv,
    float* __restrict__ out)
{
  const int idx = blockIdx.x * 256 + threadIdx.x;
  const int i = idx >> 6;
  const int c = idx & 63;
  float s = pacc[idx] + pacc[(size_t)NN * FOUT + idx];
  float r = prs[i] + prs[NN + i];
  float v = s / r;
  v = (v - bnm[c]) * rsqrtf(bnv[c] + 1e-5f) * bng[c] + bnb[c];
  out[idx] = v > 0.f ? v : expm1f(v);
}

// ---------------------------------------------------------------------------
extern "C" void kernel_launch(void* const* d_in, const int* in_sizes, int n_in,
                              void* d_out, int out_size, void* d_ws, size_t ws_size,
                              hipStream_t stream)
{
  (void)in_sizes; (void)n_in; (void)out_size; (void)ws_size;
  const float* inp = (const float*)d_in[0];
  const int*   adj = (const int*)d_in[1];
  const float* Wg  = (const float*)d_in[2];
  const float* ag  = (const float*)d_in[3];
  const float* bng = (const float*)d_in[4];
  const float* bnb = (const float*)d_in[5];
  const float* bnm = (const float*)d_in[6];
  const float* bnv = (const float*)d_in[7];
  float* out = (float*)d_out;

  char* ws = (char*)d_ws;
  unsigned short* hT = (unsigned short*)ws;                      // 1 MiB
  float* f1  = (float*)(ws + (size_t)NN * FOUT * 2);             // 32 KiB
  float* f2  = f1 + NN;                                          // 32 KiB
  float* f2m = f2 + NN;                                          // 4 B
  unsigned char* maskb = (unsigned char*)(ws + (size_t)2 * 1024 * 1024);
  unsigned long long* mask = (unsigned long long*)maskb;         // 8 MiB
  float* pacc = (float*)(ws + (size_t)10 * 1024 * 1024);         // 4 MiB
  float* prs  = (float*)(ws + (size_t)14 * 1024 * 1024);         // 64 KiB

  compress_kernel<<<2048, 256, 0, stream>>>(adj, maskb);
  prep_kernel<<<NN / 16, 256, 0, stream>>>(inp, Wg, ag, f1, f2, hT);
  f2max_kernel<<<1, 256, 0, stream>>>(f2, f2m);
  gat_main<<<(NN / TI) * 2, 256, 0, stream>>>(mask, f1, f2, f2m, hT, pacc, prs);
  epilogue_kernel<<<NN * FOUT / 256, 256, 0, stream>>>(pacc, prs, bng, bnb,
                                                       bnm, bnv, out);
}

// Round 9
// 154.047 us; speedup vs baseline: 3.0161x; 3.0161x over previous
//
#include <hip/hip_runtime.h>
#include <hip/hip_bf16.h>

#define LRALPHA 0.2f
#define L2E 1.4426950408889634f
#define NN 8192
#define FIN 128
#define FOUT 64

typedef __attribute__((ext_vector_type(4))) float f32x4;
typedef __attribute__((ext_vector_type(8))) short bf16x8;
typedef __attribute__((ext_vector_type(4))) int int4v;

// ---------------------------------------------------------------------------
// kernel 0: adj (268 MB int32) -> 1-bit mask (8 MB). Thread-linear dwordx4
// stream, measured ~6.9 TB/s (R8 diag) — at read roofline.
// maskb[i*1024 + jb] bit e = adj[i][jb*8+e] > 0.
// ---------------------------------------------------------------------------
__global__ __launch_bounds__(256) void compress_kernel(
    const int* __restrict__ adj, unsigned char* __restrict__ maskb)
{
  const int nthr = gridDim.x * 256;
  const int total = NN * (NN / 8);              // 8,388,608 byte-slots
#pragma unroll 2
  for (int idx = blockIdx.x * 256 + threadIdx.x; idx < total; idx += nthr) {
    int4v v0 = *(const int4v*)(adj + (size_t)idx * 8);
    int4v v1 = *(const int4v*)(adj + (size_t)idx * 8 + 4);
    unsigned b =
        (v0[0] > 0 ? 1u : 0u)  | (v0[1] > 0 ? 2u : 0u) |
        (v0[2] > 0 ? 4u : 0u)  | (v0[3] > 0 ? 8u : 0u) |
        (v1[0] > 0 ? 16u : 0u) | (v1[1] > 0 ? 32u : 0u) |
        (v1[2] > 0 ? 64u : 0u) | (v1[3] > 0 ? 128u : 0u);
    maskb[idx] = (unsigned char)b;
  }
}

// ---------------------------------------------------------------------------
// kernel 1: h = inp @ W (fp32), f1/f2 (prescaled by log2(e)), hT bf16
// ---------------------------------------------------------------------------
__global__ __launch_bounds__(256) void prep_kernel(
    const float* __restrict__ inp, const float* __restrict__ Wg,
    const float* __restrict__ ag, float* __restrict__ f1,
    float* __restrict__ f2, unsigned short* __restrict__ hT)
{
  __shared__ alignas(16) float WlT[FOUT][FIN + 4];
  const int t = threadIdx.x;
  for (int i = t; i < FIN * FOUT; i += 256)
    WlT[i & 63][i >> 6] = Wg[i];
  __syncthreads();

  const int lane = t & 63;
  const int row0 = blockIdx.x * 16 + (t >> 6) * 4;

  float h0 = 0.f, h1 = 0.f, h2 = 0.f, h3 = 0.f;
  for (int kk = 0; kk < FIN; kk += 4) {
    f32x4 wv = *(const f32x4*)&WlT[lane][kk];
    f32x4 r0 = *(const f32x4*)&inp[(row0 + 0) * FIN + kk];
    f32x4 r1 = *(const f32x4*)&inp[(row0 + 1) * FIN + kk];
    f32x4 r2 = *(const f32x4*)&inp[(row0 + 2) * FIN + kk];
    f32x4 r3 = *(const f32x4*)&inp[(row0 + 3) * FIN + kk];
    h0 += r0[0]*wv[0] + r0[1]*wv[1] + r0[2]*wv[2] + r0[3]*wv[3];
    h1 += r1[0]*wv[0] + r1[1]*wv[1] + r1[2]*wv[2] + r1[3]*wv[3];
    h2 += r2[0]*wv[0] + r2[1]*wv[1] + r2[2]*wv[2] + r2[3]*wv[3];
    h3 += r3[0]*wv[0] + r3[1]*wv[1] + r3[2]*wv[2] + r3[3]*wv[3];
  }

  const float a1v = ag[lane], a2v = ag[64 + lane];
  float hv[4] = {h0, h1, h2, h3};
#pragma unroll
  for (int rr = 0; rr < 4; ++rr) {
    float c1 = hv[rr] * a1v;
    float c2 = hv[rr] * a2v;
#pragma unroll
    for (int off = 32; off > 0; off >>= 1) {
      c1 += __shfl_xor(c1, off);
      c2 += __shfl_xor(c2, off);
    }
    if (lane == 0) { f1[row0 + rr] = c1 * L2E; f2[row0 + rr] = c2 * L2E; }
    __hip_bfloat16 hb = __float2bfloat16(hv[rr]);
    hT[lane * NN + row0 + rr] = __builtin_bit_cast(unsigned short, hb);
  }
}

// ---------------------------------------------------------------------------
// kernel 2: global max of (scaled) f2
// ---------------------------------------------------------------------------
__global__ __launch_bounds__(256) void f2max_kernel(
    const float* __restrict__ f2, float* __restrict__ f2m)
{
  const int t = threadIdx.x;
  float m = -1e30f;
  for (int i = t; i < NN / 4; i += 256) {
    f32x4 v = ((const f32x4*)f2)[i];
    m = fmaxf(fmaxf(m, fmaxf(v[0], v[1])), fmaxf(v[2], v[3]));
  }
#pragma unroll
  for (int off = 32; off > 0; off >>= 1)
    m = fmaxf(m, __shfl_xor(m, off));
  __shared__ float ms[4];
  if ((t & 63) == 0) ms[t >> 6] = m;
  __syncthreads();
  if (t == 0)
    f2m[0] = fmaxf(fmaxf(ms[0], ms[1]), fmaxf(ms[2], ms[3]));
}

// ---------------------------------------------------------------------------
// kernel 3: register-fragment masked-softmax attention PV + fused BN/ELU.
// NO LDS / NO barriers in the hot loop. Block = 256 thr = 4 waves = 4
// k-splits of one 16-row block. Each wave covers ALL 64 output cols
// (4 B-fragments/step), so P is produced directly in the MFMA A-fragment
// layout: lane l = row (l&15), k-slice (l>>4)*8+e -> one mask byte +
// 8 f2 floats per step. 4-slot register ring = loads consumed ~4 steps
// (~600 cyc) after issue. End: 16 KB LDS reduce across waves + BN + ELU.
// ---------------------------------------------------------------------------
__global__ __launch_bounds__(256, 2) void gat_reg(
    const unsigned char* __restrict__ maskb,
    const float* __restrict__ f1g, const float* __restrict__ f2g,
    const float* __restrict__ f2m, const unsigned short* __restrict__ hTg,
    const float* __restrict__ bng, const float* __restrict__ bnb,
    const float* __restrict__ bnm, const float* __restrict__ bnv,
    float* __restrict__ out)
{
  __shared__ alignas(16) float accl[4][16][FOUT];   // 16 KB
  __shared__ float rsl[4][16];

  const int t = threadIdx.x;
  const int l = t & 63;
  const int wv = t >> 6;                 // k-split 0..3
  const int r0 = blockIdx.x * 16;
  const int row = l & 15;
  const int g = l >> 4;                  // 0..3
  const int kbase = wv * (NN / 4);       // 2048 k per wave, 64 steps of 32

  const float f1s = f1g[r0 + row];
  const float fmv = f2m[0];
  const float M = f1s + fmv;
  const float mr = fmaxf(M, LRALPHA * M);
  const float c1 = f1s - mr;
  const float c2 = LRALPHA * f1s - mr;

  const unsigned char* mrow = maskb + (size_t)(r0 + row) * (NN / 8) + (kbase >> 3);
  const float* f2p = f2g + kbase + g * 8;
  const unsigned short* hp0 = hTg + (size_t)( 0 + row) * NN + kbase + g * 8;
  const unsigned short* hp1 = hTg + (size_t)(16 + row) * NN + kbase + g * 8;
  const unsigned short* hp2 = hTg + (size_t)(32 + row) * NN + kbase + g * 8;
  const unsigned short* hp3 = hTg + (size_t)(48 + row) * NN + kbase + g * 8;

  f32x4 acc0 = {0,0,0,0}, acc1 = {0,0,0,0}, acc2 = {0,0,0,0}, acc3 = {0,0,0,0};
  float rs = 0.f;

#define LOADD(FA, FB, B0, B1, B2, B3, S)                                       \
  { int _s = (S) < 64 ? (S) : 63;                                              \
    FA = *(const f32x4*)(f2p + _s * 32);                                       \
    FB = *(const f32x4*)(f2p + _s * 32 + 4);                                   \
    B0 = *(const bf16x8*)(hp0 + _s * 32);                                      \
    B1 = *(const bf16x8*)(hp1 + _s * 32);                                      \
    B2 = *(const bf16x8*)(hp2 + _s * 32);                                      \
    B3 = *(const bf16x8*)(hp3 + _s * 32); }

#define STEPC(FA, FB, B0, B1, B2, B3, MB)                                      \
  {                                                                            \
    const unsigned _mb = (MB);                                                 \
    float z0 = fmaxf(c1 + FA[0], c2 + LRALPHA * FA[0]);                        \
    float z1 = fmaxf(c1 + FA[1], c2 + LRALPHA * FA[1]);                        \
    float z2 = fmaxf(c1 + FA[2], c2 + LRALPHA * FA[2]);                        \
    float z3 = fmaxf(c1 + FA[3], c2 + LRALPHA * FA[3]);                        \
    float z4 = fmaxf(c1 + FB[0], c2 + LRALPHA * FB[0]);                        \
    float z5 = fmaxf(c1 + FB[1], c2 + LRALPHA * FB[1]);                        \
    float z6 = fmaxf(c1 + FB[2], c2 + LRALPHA * FB[2]);                        \
    float z7 = fmaxf(c1 + FB[3], c2 + LRALPHA * FB[3]);                        \
    z0 = (_mb & 1u)   ? z0 : -1000.f;                                          \
    z1 = (_mb & 2u)   ? z1 : -1000.f;                                          \
    z2 = (_mb & 4u)   ? z2 : -1000.f;                                          \
    z3 = (_mb & 8u)   ? z3 : -1000.f;                                          \
    z4 = (_mb & 16u)  ? z4 : -1000.f;                                          \
    z5 = (_mb & 32u)  ? z5 : -1000.f;                                          \
    z6 = (_mb & 64u)  ? z6 : -1000.f;                                          \
    z7 = (_mb & 128u) ? z7 : -1000.f;                                          \
    float p0 = __builtin_amdgcn_exp2f(z0);                                     \
    float p1 = __builtin_amdgcn_exp2f(z1);                                     \
    float p2 = __builtin_amdgcn_exp2f(z2);                                     \
    float p3 = __builtin_amdgcn_exp2f(z3);                                     \
    float p4 = __builtin_amdgcn_exp2f(z4);                                     \
    float p5 = __builtin_amdgcn_exp2f(z5);                                     \
    float p6 = __builtin_amdgcn_exp2f(z6);                                     \
    float p7 = __builtin_amdgcn_exp2f(z7);                                     \
    rs += ((p0 + p1) + (p2 + p3)) + ((p4 + p5) + (p6 + p7));                   \
    unsigned q0 = __builtin_bit_cast(unsigned, p0) + 0x8000u;                  \
    unsigned q1 = __builtin_bit_cast(unsigned, p1) + 0x8000u;                  \
    unsigned q2 = __builtin_bit_cast(unsigned, p2) + 0x8000u;                  \
    unsigned q3 = __builtin_bit_cast(unsigned, p3) + 0x8000u;                  \
    unsigned q4 = __builtin_bit_cast(unsigned, p4) + 0x8000u;                  \
    unsigned q5 = __builtin_bit_cast(unsigned, p5) + 0x8000u;                  \
    unsigned q6 = __builtin_bit_cast(unsigned, p6) + 0x8000u;                  \
    unsigned q7 = __builtin_bit_cast(unsigned, p7) + 0x8000u;                  \
    unsigned d0 = __builtin_amdgcn_perm(q1, q0, 0x07060302u);                  \
    unsigned d1 = __builtin_amdgcn_perm(q3, q2, 0x07060302u);                  \
    unsigned d2 = __builtin_amdgcn_perm(q5, q4, 0x07060302u);                  \
    unsigned d3 = __builtin_amdgcn_perm(q7, q6, 0x07060302u);                  \
    int4v pw = {(int)d0, (int)d1, (int)d2, (int)d3};                           \
    bf16x8 av = __builtin_bit_cast(bf16x8, pw);                                \
    acc0 = __builtin_amdgcn_mfma_f32_16x16x32_bf16(av, B0, acc0, 0, 0, 0);     \
    acc1 = __builtin_amdgcn_mfma_f32_16x16x32_bf16(av, B1, acc1, 0, 0, 0);     \
    acc2 = __builtin_amdgcn_mfma_f32_16x16x32_bf16(av, B2, acc2, 0, 0, 0);     \
    acc3 = __builtin_amdgcn_mfma_f32_16x16x32_bf16(av, B3, acc3, 0, 0, 0);     \
  }

  // 4 ring slots (named, statically indexed — rule #20)
  f32x4 fa0, fb0, fa1, fb1, fa2, fb2, fa3, fb3;
  bf16x8 b00, b10, b20, b30, b01, b11, b21, b31;
  bf16x8 b02, b12, b22, b32, b03, b13, b23, b33;

  int4v mwA = *(const int4v*)(mrow);        // mask dwords, steps 0..3
  int4v mwB = *(const int4v*)(mrow + 16);   // steps 4..7
  LOADD(fa0, fb0, b00, b10, b20, b30, 0);
  LOADD(fa1, fb1, b01, b11, b21, b31, 1);
  LOADD(fa2, fb2, b02, b12, b22, b32, 2);
  LOADD(fa3, fb3, b03, b13, b23, b33, 3);

  for (int sg = 0; sg < 16; ++sg) {
    const int sb = sg * 4;
    const unsigned mb0 = ((unsigned)mwA[0] >> (g * 8)) & 0xFFu;
    const unsigned mb1 = ((unsigned)mwA[1] >> (g * 8)) & 0xFFu;
    const unsigned mb2 = ((unsigned)mwA[2] >> (g * 8)) & 0xFFu;
    const unsigned mb3 = ((unsigned)mwA[3] >> (g * 8)) & 0xFFu;
    mwA = mwB;
    { const int _g2 = sg + 2 < 16 ? sg + 2 : 15;
      mwB = *(const int4v*)(mrow + _g2 * 16); }
    STEPC(fa0, fb0, b00, b10, b20, b30, mb0);
    LOADD(fa0, fb0, b00, b10, b20, b30, sb + 4);
    STEPC(fa1, fb1, b01, b11, b21, b31, mb1);
    LOADD(fa1, fb1, b01, b11, b21, b31, sb + 5);
    STEPC(fa2, fb2, b02, b12, b22, b32, mb2);
    LOADD(fa2, fb2, b02, b12, b22, b32, sb + 6);
    STEPC(fa3, fb3, b03, b13, b23, b33, mb3);
    LOADD(fa3, fb3, b03, b13, b23, b33, sb + 7);
  }
#undef STEPC
#undef LOADD

  // row-sum: lanes l, l+16, l+32, l+48 hold the same row's partials
  rs += __shfl_xor(rs, 16);
  rs += __shfl_xor(rs, 32);
  if (l < 16) rsl[wv][l] = rs;

  // C layout: lane l holds C[g*4+q][l&15] per col-group
#pragma unroll
  for (int q = 0; q < 4; ++q) {
    accl[wv][g * 4 + q][ 0 + row] = acc0[q];
    accl[wv][g * 4 + q][16 + row] = acc1[q];
    accl[wv][g * 4 + q][32 + row] = acc2[q];
    accl[wv][g * 4 + q][48 + row] = acc3[q];
  }
  __syncthreads();

  // fused combine (4 k-splits) + BN + ELU; thread t -> row i, cols c..c+3
  const int i = t >> 4;
  const int c = (t & 15) * 4;
  f32x4 s0 = *(const f32x4*)&accl[0][i][c];
  f32x4 s1 = *(const f32x4*)&accl[1][i][c];
  f32x4 s2 = *(const f32x4*)&accl[2][i][c];
  f32x4 s3 = *(const f32x4*)&accl[3][i][c];
  const float r = rsl[0][i] + rsl[1][i] + rsl[2][i] + rsl[3][i];
  f32x4 ov;
#pragma unroll
  for (int e = 0; e < 4; ++e) {
    float v = ((s0[e] + s1[e]) + (s2[e] + s3[e])) / r;
    v = (v - bnm[c + e]) * rsqrtf(bnv[c + e] + 1e-5f) * bng[c + e] + bnb[c + e];
    ov[e] = v > 0.f ? v : expm1f(v);
  }
  *(f32x4*)&out[(size_t)(r0 + i) * FOUT + c] = ov;
}

// ---------------------------------------------------------------------------
extern "C" void kernel_launch(void* const* d_in, const int* in_sizes, int n_in,
                              void* d_out, int out_size, void* d_ws, size_t ws_size,
                              hipStream_t stream)
{
  (void)in_sizes; (void)n_in; (void)out_size; (void)ws_size;
  const float* inp = (const float*)d_in[0];
  const int*   adj = (const int*)d_in[1];
  const float* Wg  = (const float*)d_in[2];
  const float* ag  = (const float*)d_in[3];
  const float* bng = (const float*)d_in[4];
  const float* bnb = (const float*)d_in[5];
  const float* bnm = (const float*)d_in[6];
  const float* bnv = (const float*)d_in[7];
  float* out = (float*)d_out;

  char* ws = (char*)d_ws;
  unsigned short* hT = (unsigned short*)ws;                      // 1 MiB
  float* f1  = (float*)(ws + (size_t)NN * FOUT * 2);             // 32 KiB
  float* f2  = f1 + NN;                                          // 32 KiB
  float* f2m = f2 + NN;                                          // 4 B
  unsigned char* maskb = (unsigned char*)(ws + (size_t)2 * 1024 * 1024); // 8 MiB

  compress_kernel<<<2048, 256, 0, stream>>>(adj, maskb);
  prep_kernel<<<NN / 16, 256, 0, stream>>>(inp, Wg, ag, f1, f2, hT);
  f2max_kernel<<<1, 256, 0, stream>>>(f2, f2m);
  gat_reg<<<NN / 16, 256, 0, stream>>>(maskb, f1, f2, f2m, hT,
                                       bng, bnb, bnm, bnv, out);
}

// Round 10
// 144.839 us; speedup vs baseline: 3.2079x; 1.0636x over previous
//
#include <hip/hip_runtime.h>
#include <hip/hip_bf16.h>

#define LRALPHA 0.2f
#define L2E 1.4426950408889634f
#define NN 8192
#define FIN 128
#define FOUT 64
#define TI 16
#define TJ 128
#define NQ 4                 // j-quarters
#define TPB 16               // tiles per block: (NN/TJ)/NQ

typedef __attribute__((ext_vector_type(2))) float f32x2;
typedef __attribute__((ext_vector_type(4))) float f32x4;
typedef __attribute__((ext_vector_type(8))) short bf16x8;
typedef __attribute__((ext_vector_type(4))) int int4v;

__device__ __forceinline__ void barrier_lgkm() {
  asm volatile("s_waitcnt lgkmcnt(0)\n\ts_barrier" ::: "memory");
}

// ---------------------------------------------------------------------------
// kernel 0: adj (268 MB int32) -> 1-bit mask (8 MB). Thread-linear dwordx4
// stream, measured ~6.9 TB/s (R8 diag) — at read roofline.
// maskb[i*1024 + jb] bit e = adj[i][jb*8+e] > 0.
// ---------------------------------------------------------------------------
__global__ __launch_bounds__(256) void compress_kernel(
    const int* __restrict__ adj, unsigned char* __restrict__ maskb)
{
  const int nthr = gridDim.x * 256;
  const int total = NN * (NN / 8);
#pragma unroll 2
  for (int idx = blockIdx.x * 256 + threadIdx.x; idx < total; idx += nthr) {
    int4v v0 = *(const int4v*)(adj + (size_t)idx * 8);
    int4v v1 = *(const int4v*)(adj + (size_t)idx * 8 + 4);
    unsigned b =
        (v0[0] > 0 ? 1u : 0u)  | (v0[1] > 0 ? 2u : 0u) |
        (v0[2] > 0 ? 4u : 0u)  | (v0[3] > 0 ? 8u : 0u) |
        (v1[0] > 0 ? 16u : 0u) | (v1[1] > 0 ? 32u : 0u) |
        (v1[2] > 0 ? 64u : 0u) | (v1[3] > 0 ? 128u : 0u);
    maskb[idx] = (unsigned char)b;
  }
}

// ---------------------------------------------------------------------------
// kernel 1: h = inp @ W (fp32), f1/f2 (prescaled by log2(e)), hT bf16
// ---------------------------------------------------------------------------
__global__ __launch_bounds__(256) void prep_kernel(
    const float* __restrict__ inp, const float* __restrict__ Wg,
    const float* __restrict__ ag, float* __restrict__ f1,
    float* __restrict__ f2, unsigned short* __restrict__ hT)
{
  __shared__ alignas(16) float WlT[FOUT][FIN + 4];
  const int t = threadIdx.x;
  for (int i = t; i < FIN * FOUT; i += 256)
    WlT[i & 63][i >> 6] = Wg[i];
  __syncthreads();

  const int lane = t & 63;
  const int row0 = blockIdx.x * 16 + (t >> 6) * 4;

  float h0 = 0.f, h1 = 0.f, h2 = 0.f, h3 = 0.f;
  for (int kk = 0; kk < FIN; kk += 4) {
    f32x4 wv = *(const f32x4*)&WlT[lane][kk];
    f32x4 r0 = *(const f32x4*)&inp[(row0 + 0) * FIN + kk];
    f32x4 r1 = *(const f32x4*)&inp[(row0 + 1) * FIN + kk];
    f32x4 r2 = *(const f32x4*)&inp[(row0 + 2) * FIN + kk];
    f32x4 r3 = *(const f32x4*)&inp[(row0 + 3) * FIN + kk];
    h0 += r0[0]*wv[0] + r0[1]*wv[1] + r0[2]*wv[2] + r0[3]*wv[3];
    h1 += r1[0]*wv[0] + r1[1]*wv[1] + r1[2]*wv[2] + r1[3]*wv[3];
    h2 += r2[0]*wv[0] + r2[1]*wv[1] + r2[2]*wv[2] + r2[3]*wv[3];
    h3 += r3[0]*wv[0] + r3[1]*wv[1] + r3[2]*wv[2] + r3[3]*wv[3];
  }

  const float a1v = ag[lane], a2v = ag[64 + lane];
  float hv[4] = {h0, h1, h2, h3};
#pragma unroll
  for (int rr = 0; rr < 4; ++rr) {
    float c1 = hv[rr] * a1v;
    float c2 = hv[rr] * a2v;
#pragma unroll
    for (int off = 32; off > 0; off >>= 1) {
      c1 += __shfl_xor(c1, off);
      c2 += __shfl_xor(c2, off);
    }
    if (lane == 0) { f1[row0 + rr] = c1 * L2E; f2[row0 + rr] = c2 * L2E; }
    __hip_bfloat16 hb = __float2bfloat16(hv[rr]);
    hT[lane * NN + row0 + rr] = __builtin_bit_cast(unsigned short, hb);
  }
}

// ---------------------------------------------------------------------------
// kernel 2: global max of (scaled) f2
// ---------------------------------------------------------------------------
__global__ __launch_bounds__(256) void f2max_kernel(
    const float* __restrict__ f2, float* __restrict__ f2m)
{
  const int t = threadIdx.x;
  float m = -1e30f;
  for (int i = t; i < NN / 4; i += 256) {
    f32x4 v = ((const f32x4*)f2)[i];
    m = fmaxf(fmaxf(m, fmaxf(v[0], v[1])), fmaxf(v[2], v[3]));
  }
#pragma unroll
  for (int off = 32; off > 0; off >>= 1)
    m = fmaxf(m, __shfl_xor(m, off));
  __shared__ float ms[4];
  if ((t & 63) == 0) ms[t >> 6] = m;
  __syncthreads();
  if (t == 0)
    f2m[0] = fmaxf(fmaxf(ms[0], ms[1]), fmaxf(ms[2], ms[3]));
}

// ---------------------------------------------------------------------------
// kernel 3: R7 structure at 2x the occupancy. TJ=128 -> Pl quad-buffer =
// 17.4 KB -> 8 blocks/CU (grid 2048 = 512 rowblocks x 4 j-quarters, exact).
// VGPR target <=64 (launch_bounds(256,8)) -> 32 waves/CU. One lgkm-barrier
// per tile; produce-lead-2 / load-lead-3 quad-buffer pipeline; B-fragments
// read directly from L2-resident hT. Partials -> ws; epilogue combines.
// ---------------------------------------------------------------------------
__global__ __launch_bounds__(256, 8) void gat_main(
    const unsigned* __restrict__ mask32,
    const float* __restrict__ f1g, const float* __restrict__ f2g,
    const float* __restrict__ f2m, const unsigned short* __restrict__ hTg,
    float* __restrict__ pacc, float* __restrict__ prs)
{
  __shared__ alignas(16) unsigned short Pl[4][TI][TJ + 8];  // 17408 B

  const int t = threadIdx.x;
  const int l = t & 63;
  const int w = t >> 6;
  const int rb = blockIdx.x >> 2;        // rowblock 0..511
  const int h  = blockIdx.x & 3;         // j-quarter 0..3
  const int i0 = rb * TI;
  const int g  = l >> 4;                 // 0..3
  const int row = l & 15;

  const float fmv = f2m[0];
  float c1q[4], c2q[4];
#pragma unroll
  for (int q = 0; q < 4; ++q) {
    float f1s = f1g[i0 + 4 * w + q];
    float M = f1s + fmv;
    float mr = fmaxf(M, LRALPHA * M);
    c1q[q] = f1s - mr;
    c2q[q] = LRALPHA * f1s - mr;
  }

  // mask dword for row (i0+4w+q), tile k of quarter h, dword-sub g:
  // mask32[row*256 + h*64 + k*4 + g]
  const unsigned* mb0 = mask32 + (size_t)(i0 + 4*w + 0) * 256 + h * 64 + g;
  const unsigned* mb1 = mask32 + (size_t)(i0 + 4*w + 1) * 256 + h * 64 + g;
  const unsigned* mb2 = mask32 + (size_t)(i0 + 4*w + 2) * 256 + h * 64 + g;
  const unsigned* mb3 = mask32 + (size_t)(i0 + 4*w + 3) * 256 + h * 64 + g;
  const int bsh = 2 * row;               // bit shift for this lane's col pair

  const float* f2p = f2g + h * 2048 + 2 * l;
  const unsigned short* hp = hTg + (size_t)(w * 16 + row) * NN + h * 2048 + g * 8;

  f32x4 acc = {0.f, 0.f, 0.f, 0.f};
  float rs0 = 0.f, rs1 = 0.f, rs2 = 0.f, rs3 = 0.f;

#define PRODUCE(K, M0, M1, M2, M3, FF)                                         \
  {                                                                            \
    const float F0 = FF[0], F1 = FF[1];                                        \
    const float F5a = LRALPHA * F0, F5b = LRALPHA * F1;                        \
    _Pragma("unroll")                                                          \
    for (int q = 0; q < 4; ++q) {                                              \
      const unsigned mm = (q == 0 ? M0 : q == 1 ? M1 : q == 2 ? M2 : M3);      \
      const unsigned bb = (mm >> bsh) & 3u;                                    \
      float z0 = fmaxf(c1q[q] + F0, c2q[q] + F5a);                             \
      float z1 = fmaxf(c1q[q] + F1, c2q[q] + F5b);                             \
      z0 = (bb & 1u) ? z0 : -1000.f;                                           \
      z1 = (bb & 2u) ? z1 : -1000.f;                                           \
      float p0 = __builtin_amdgcn_exp2f(z0);                                   \
      float p1 = __builtin_amdgcn_exp2f(z1);                                   \
      if (q == 0) rs0 += p0 + p1;                                              \
      else if (q == 1) rs1 += p0 + p1;                                         \
      else if (q == 2) rs2 += p0 + p1;                                         \
      else rs3 += p0 + p1;                                                     \
      unsigned q0 = __builtin_bit_cast(unsigned, p0) + 0x8000u;                \
      unsigned q1 = __builtin_bit_cast(unsigned, p1) + 0x8000u;                \
      unsigned pk = __builtin_amdgcn_perm(q1, q0, 0x07060302u);                \
      *(unsigned*)&Pl[(K) & 3][4 * w + q][2 * l] = pk;                         \
    }                                                                          \
  }

#define LOADR(M0, M1, M2, M3, FF, K)                                           \
  { const int _k = (K) < TPB ? (K) : (TPB - 1);                                \
    M0 = mb0[_k * 4]; M1 = mb1[_k * 4];                                        \
    M2 = mb2[_k * 4]; M3 = mb3[_k * 4];                                        \
    FF = *(const f32x2*)(f2p + _k * TJ); }

  unsigned m0, m1, m2, m3;
  f32x2 ff;

  LOADR(m0, m1, m2, m3, ff, 0);
  PRODUCE(0, m0, m1, m2, m3, ff);
  LOADR(m0, m1, m2, m3, ff, 1);
  PRODUCE(1, m0, m1, m2, m3, ff);
  LOADR(m0, m1, m2, m3, ff, 2);

  for (int k = 0; k < TPB; ++k) {
    if (k < TPB - 2) {
      PRODUCE(k + 2, m0, m1, m2, m3, ff);
      LOADR(m0, m1, m2, m3, ff, k + 3);
    }
    barrier_lgkm();
    const unsigned short* pa = &Pl[k & 3][0][0] + row * (TJ + 8) + g * 8;
    const unsigned short* pb = hp + (size_t)k * TJ;
#pragma unroll
    for (int kw = 0; kw < 4; ++kw) {
      bf16x8 av = *(const bf16x8*)(pa + kw * 32);
      bf16x8 bv = *(const bf16x8*)(pb + kw * 32);
      acc = __builtin_amdgcn_mfma_f32_16x16x32_bf16(av, bv, acc, 0, 0, 0);
    }
  }
#undef PRODUCE
#undef LOADR

  // wave-level row sums -> partial rs for this quarter
  float rsq[4] = {rs0, rs1, rs2, rs3};
#pragma unroll
  for (int q = 0; q < 4; ++q) {
    float r = rsq[q];
#pragma unroll
    for (int off = 32; off > 0; off >>= 1)
      r += __shfl_xor(r, off);
    if (l == 0) prs[(size_t)h * NN + i0 + 4 * w + q] = r;
  }

  // partial acc: row = g*4 + q, col = w*16 + row
  float* po = pacc + (size_t)h * NN * FOUT
            + (size_t)(i0 + g * 4) * FOUT + (w * 16 + row);
#pragma unroll
  for (int q = 0; q < 4; ++q)
    po[(size_t)q * FOUT] = acc[q];
}

// ---------------------------------------------------------------------------
// kernel 4: combine 4 quarters, BN, ELU
// ---------------------------------------------------------------------------
__global__ __launch_bounds__(256) void epilogue_kernel(
    const float* __restrict__ pacc, const float* __restrict__ prs,
    const float* __restrict__ bng, const float* __restrict__ bnb,
    const float* __restrict__ bnm, const float* __restrict__ bnv,
    float* __restrict__ out)
{
  const int idx = blockIdx.x * 256 + threadIdx.x;
  const int i = idx >> 6;
  const int c = idx & 63;
  float s = 0.f, r = 0.f;
#pragma unroll
  for (int h = 0; h < NQ; ++h) {
    s += pacc[(size_t)h * NN * FOUT + idx];
    r += prs[(size_t)h * NN + i];
  }
  float v = s / r;
  v = (v - bnm[c]) * rsqrtf(bnv[c] + 1e-5f) * bng[c] + bnb[c];
  out[idx] = v > 0.f ? v : expm1f(v);
}

// ---------------------------------------------------------------------------
extern "C" void kernel_launch(void* const* d_in, const int* in_sizes, int n_in,
                              void* d_out, int out_size, void* d_ws, size_t ws_size,
                              hipStream_t stream)
{
  (void)in_sizes; (void)n_in; (void)out_size; (void)ws_size;
  const float* inp = (const float*)d_in[0];
  const int*   adj = (const int*)d_in[1];
  const float* Wg  = (const float*)d_in[2];
  const float* ag  = (const float*)d_in[3];
  const float* bng = (const float*)d_in[4];
  const float* bnb = (const float*)d_in[5];
  const float* bnm = (const float*)d_in[6];
  const float* bnv = (const float*)d_in[7];
  float* out = (float*)d_out;

  char* ws = (char*)d_ws;
  unsigned short* hT = (unsigned short*)ws;                      // 1 MiB
  float* f1  = (float*)(ws + (size_t)NN * FOUT * 2);             // 32 KiB
  float* f2  = f1 + NN;                                          // 32 KiB
  float* f2m = f2 + NN;                                          // 4 B
  unsigned char* maskb = (unsigned char*)(ws + (size_t)2 * 1024 * 1024); // 8 MiB
  float* pacc = (float*)(ws + (size_t)10 * 1024 * 1024);         // 8 MiB
  float* prs  = (float*)(ws + (size_t)18 * 1024 * 1024);         // 128 KiB

  compress_kernel<<<2048, 256, 0, stream>>>(adj, maskb);
  prep_kernel<<<NN / 16, 256, 0, stream>>>(inp, Wg, ag, f1, f2, hT);
  f2max_kernel<<<1, 256, 0, stream>>>(f2, f2m);
  gat_main<<<(NN / TI) * NQ, 256, 0, stream>>>((const unsigned*)maskb,
                                               f1, f2, f2m, hT, pacc, prs);
  epilogue_kernel<<<NN * FOUT / 256, 256, 0, stream>>>(pacc, prs, bng, bnb,
                                                       bnm, bnv, out);
}